// Round 5
// baseline (418.710 us; speedup 1.0000x reference)
//
#include <hip/hip_runtime.h>
#include <math.h>

// CRF log-likelihood, B=512, S=512, T=128.
// fwd_kernel: 1 block (512 thr, 8 waves) per batch; thread (r=tid&3, c=tid>>2)
// owns E rows [32r,32r+32) x col c as float4 Efr[8].
// ROUND 5: the 32 MACs are inline-asm v_fmac_f32 with "v" constraints --
// round 4's VGPR_Count=36 proved the compiler offloaded Efr to AGPRs
// (32 floats can't fit 36 VGPRs), taxing every step with accvgpr moves
// (VALUBusy 72% at 4x the fma floor). The asm pins E's live range to arch
// VGPRs. Score update is now computed by ALL r-lanes (no divergent ALU
// block; only the p-write is masked); denominator sum scaled by 0.25 for
// the 4x duplication.
// p double-buffered in LDS, plain layout; conflict-free ROTATED read order
// idx[i] = 8r + ((i+2r)&7) (round 4: SQ_LDS_BANK_CONFLICT = 0). Efr[i]
// holds rows 4*idx[i]..+3 to match. ONE barrier per step.
// sigma shift = col-0 score, 1-step delayed via sig_sh (any consistent
// shift is exact; exp args bounded ~e^20, fp32-safe).

#define T 128
#define SLEN 512
#define BATCH 512

__global__ __launch_bounds__(512, 4) void fwd_kernel(
    const float* __restrict__ em, const int* __restrict__ tags,
    const int* __restrict__ mask, const float* __restrict__ startT,
    const float* __restrict__ endT, const float* __restrict__ trans,
    float* __restrict__ ws)
{
    const int b   = blockIdx.x;
    const int tid = threadIdx.x;
    const int r   = tid & 3;          // row group: rows [32r, 32r+32)
    const int c   = tid >> 2;         // column 0..127
    const float* emb = em + (size_t)b * SLEN * T;
    const int*   mk  = mask + (size_t)b * SLEN;

    // Per-thread read schedule (conflict-free rotation) + matching E fragment.
    int idx[8];
#pragma unroll
    for (int i = 0; i < 8; ++i) idx[i] = 8 * r + ((i + 2 * r) & 7);

    float4 Efr[8];
#pragma unroll
    for (int i = 0; i < 8; ++i) {
        const int row0 = 4 * idx[i];
        Efr[i].x = __expf(trans[(row0 + 0) * T + c]);
        Efr[i].y = __expf(trans[(row0 + 1) * T + c]);
        Efr[i].z = __expf(trans[(row0 + 2) * T + c]);
        Efr[i].w = __expf(trans[(row0 + 3) * T + c]);
    }

    __shared__ __align__(16) float4 psh4[2][T / 4];   // plain: elem c at word c
    __shared__ float sig_sh[2];
    __shared__ float redm[8], reds[8], redn[8];
    __shared__ int   redc[8];

    // alpha_0 -- all lanes compute; r==0 lane writes p
    float score = startT[c] + emb[c];
    if (r == 0) ((float*)&psh4[1][0])[c] = __expf(score);
    if (tid == 0) sig_sh[1] = score;
    float sigma = 0.f;

    // 4-deep emission/mask prefetch
    float emv[4], emn[4];
    int   mkv[4], mkn[4];
#pragma unroll
    for (int k = 0; k < 4; ++k) { emv[k] = emb[(1 + k) * T + c]; mkv[k] = mk[1 + k]; }
    __syncthreads();

#define FMA_V(acc, p, e) \
    asm("v_fmac_f32 %0, %1, %2" : "+v"(acc) : "v"(p), "v"(e))

    for (int s0 = 1; s0 < SLEN; s0 += 4) {
#pragma unroll
        for (int k = 0; k < 4; ++k) {
            int ss = s0 + 4 + k; ss = (ss < SLEN) ? ss : (SLEN - 1);
            emn[k] = emb[ss * T + c];
            mkn[k] = mk[ss];
        }
#pragma unroll
        for (int k = 0; k < 4; ++k) {
            const int s = s0 + k;
            if (s < SLEN) {                        // uniform guard (511 steps)
                const int cur = (1 + k) & 1;       // == s&1: compile-time
                float a0 = 0.f, a1 = 0.f, a2 = 0.f, a3 = 0.f;
#pragma unroll
                for (int i = 0; i < 8; ++i) {
                    const float4 pv = psh4[cur][idx[i]];   // conflict-free
                    FMA_V(a0, pv.x, Efr[i].x);
                    FMA_V(a1, pv.y, Efr[i].y);
                    FMA_V(a2, pv.z, Efr[i].z);
                    FMA_V(a3, pv.w, Efr[i].w);
                }
                float t = (a0 + a1) + (a2 + a3);
                t += __shfl_xor(t, 1);             // reduce over r (bits 0,1)
                t += __shfl_xor(t, 2);             // all 4 r-lanes hold full sum
                const float sig_next = sig_sh[cur];
                // non-divergent score update (identical across r-lanes)
                const float n = sigma + __logf(t) + emv[k];
                score = (mkv[k] > 0) ? n : score;
                const float pp = __expf(score - sig_next);
                if (r == 0) ((float*)&psh4[cur ^ 1][0])[c] = pp;
                if (tid == 0) sig_sh[cur ^ 1] = score;
                sigma = sig_next;
                __syncthreads();
            }
        }
#pragma unroll
        for (int k = 0; k < 4; ++k) { emv[k] = emn[k]; mkv[k] = mkn[k]; }
    }

    // ---- denominator: logsumexp_c(score_c + endT_c) ----
    // score valid in ALL lanes (duplicated 4x across r) -> scale sum by 0.25.
    const int wid = tid >> 6, lane = tid & 63;
    float v = score + endT[c];
    float m = v;
#pragma unroll
    for (int off = 32; off; off >>= 1) m = fmaxf(m, __shfl_xor(m, off));
    if (lane == 0) redm[wid] = m;
    __syncthreads();
    float M = redm[0];
#pragma unroll
    for (int i = 1; i < 8; ++i) M = fmaxf(M, redm[i]);
    float sm = __expf(v - M);
#pragma unroll
    for (int off = 32; off; off >>= 1) sm += __shfl_xor(sm, off);
    if (lane == 0) reds[wid] = sm;

    // ---- numerator: one sequence step per thread ----
    const int* tg = tags + (size_t)b * SLEN;
    const int mm = mk[tid];
    int   cnt = (mm != 0);
    float nv  = 0.f;
    if (tid >= 1 && mm > 0)
        nv = trans[tg[tid - 1] * T + tg[tid]] + emb[tid * T + tg[tid]];
#pragma unroll
    for (int off = 32; off; off >>= 1) {
        nv  += __shfl_xor(nv, off);
        cnt += __shfl_xor(cnt, off);
    }
    if (lane == 0) { redn[wid] = nv; redc[wid] = cnt; }
    __syncthreads();
    if (tid == 0) {
        float ssum = 0.f, nsum = 0.f; int seqlen = 0;
#pragma unroll
        for (int i = 0; i < 8; ++i) { ssum += reds[i]; nsum += redn[i]; seqlen += redc[i]; }
        const float denom = M + __logf(ssum * 0.25f);
        const int t0 = tg[0], tl = tg[seqlen - 1];
        ws[b] = (startT[t0] + emb[t0] + endT[tl] + nsum) - denom;
    }
}

__global__ __launch_bounds__(256) void reduce_kernel(
    const float* __restrict__ ws, float* __restrict__ out)
{
    const int t = threadIdx.x;          // one block of 256
    float local = 0.f;
    for (int i = t; i < BATCH; i += 256) local += ws[i];
    __shared__ float rf[256];
    rf[t] = local;
    __syncthreads();
    for (int off = 128; off > 0; off >>= 1) {
        if (t < off) rf[t] += rf[t + off];
        __syncthreads();
    }
    if (t == 0) out[0] = rf[0];
}

extern "C" void kernel_launch(void* const* d_in, const int* in_sizes, int n_in,
                              void* d_out, int out_size, void* d_ws, size_t ws_size,
                              hipStream_t stream)
{
    const float* emissions = (const float*)d_in[0];
    const int*   tags      = (const int*)d_in[1];
    const int*   mask      = (const int*)d_in[2];
    const float* startT    = (const float*)d_in[3];
    const float* endT      = (const float*)d_in[4];
    const float* trans     = (const float*)d_in[5];
    float* out = (float*)d_out;
    float* ws  = (float*)d_ws;          // BATCH floats of per-batch partials

    fwd_kernel<<<BATCH, 512, 0, stream>>>(emissions, tags, mask, startT, endT, trans, ws);
    reduce_kernel<<<1, 256, 0, stream>>>(ws, out);
}

// Round 6
// 409.481 us; speedup vs baseline: 1.0225x; 1.0225x over previous
//
#include <hip/hip_runtime.h>
#include <math.h>

// CRF log-likelihood, B=512, S=512, T=128.
// ROUND 6: LDS-volume fix. R5 post-mortem: broadcast ds_read_b128 still pays
// full 1KB return bandwidth (16 waves x 8 b128 x ~11cyc = ~1450 cyc/step ==
// observed 1417). Volume = 4B/MAC at C=1 col/thread. This round: C=4.
// Block = 512 thr = TWO batches (h=tid>>8); per batch 256 thr:
//   rg=u&7 (8 row-groups of 16 rows), cg=u>>3 (32 col-groups of 4 cols).
//   E fragment: 4 cols x 16 rows = 16 float4 (AGPR residence is fine -- R5
//   proved VALU reads acc-resident values at full rate; pin changed nothing).
// p in LDS as 32 float4 chunks per [h][buf]; conflict-free via
//   (a) rotated read order craw[i] = 4rg + ((i+rg)&3)
//   (b) xor storage swizzle slot = craw ^ ((craw&16)?4:0)
//   -> per instruction the 8 rg-groups hit 8 DISTINCT bank-quads (enumerated).
// Cross-rg reduce: 3-shuffle value-routing butterfly (xor1,xor2 route the 4
// accumulators so lane rg ends with ITS col (q=rg&3) total; xor4 finishes).
// One barrier/step. sigma shift = col-0 score, 1-step delayed via sig_sh.

#define T 128
#define SLEN 512
#define BATCH 512

__global__ __launch_bounds__(512, 2) void fwd_kernel(
    const float* __restrict__ em, const int* __restrict__ tags,
    const int* __restrict__ mask, const float* __restrict__ startT,
    const float* __restrict__ endT, const float* __restrict__ trans,
    float* __restrict__ ws)
{
    const int tid = threadIdx.x;
    const int h   = tid >> 8;          // batch half
    const int u   = tid & 255;
    const int rg  = u & 7;             // row group: 16 rows
    const int cg  = u >> 3;            // col group: 4 cols (0..31)
    const int q   = rg & 3;            // this lane's score column within group
    const int b   = 2 * blockIdx.x + h;
    const int jc  = 4 * cg + q;        // score column
    const float* emb = em + (size_t)b * SLEN * T;
    const int*   mk  = mask + (size_t)b * SLEN;

    // Chunk schedule: 4 chunks of 4 rows; rotated + storage-swizzled.
    int craw[4], slot[4];
#pragma unroll
    for (int i = 0; i < 4; ++i) {
        craw[i] = 4 * rg + ((i + rg) & 3);
        slot[i] = craw[i] ^ ((craw[i] & 16) ? 4 : 0);
    }

    // E fragment: Ef[i][qq] = exp(trans[4*craw[i]+k][4cg+qq]), k=0..3 in xyzw.
    float4 Ef[4][4];
#pragma unroll
    for (int i = 0; i < 4; ++i) {
        const int r0 = 4 * craw[i];
#pragma unroll
        for (int qq = 0; qq < 4; ++qq) {
            const int col = 4 * cg + qq;
            Ef[i][qq].x = __expf(trans[(r0 + 0) * T + col]);
            Ef[i][qq].y = __expf(trans[(r0 + 1) * T + col]);
            Ef[i][qq].z = __expf(trans[(r0 + 2) * T + col]);
            Ef[i][qq].w = __expf(trans[(r0 + 3) * T + col]);
        }
    }

    __shared__ __align__(16) float4 psh[2][2][32];   // [h][buf][slot]
    __shared__ float sig_sh[2][2];                   // [h][buf]
    __shared__ float redm[8], reds[8], redn[8];
    __shared__ int   redc[8];

    // Precomputed LDS addresses (no per-step address VALU).
    const float4* paddr[2][4];
#pragma unroll
    for (int buf = 0; buf < 2; ++buf)
#pragma unroll
        for (int i = 0; i < 4; ++i) paddr[buf][i] = &psh[h][buf][slot[i]];
    const int scg = cg ^ ((cg & 16) ? 4 : 0);        // write slot for col jc
    float* wptr[2] = { (float*)&psh[h][0][scg] + q,
                       (float*)&psh[h][1][scg] + q };

    // alpha_0
    float score = startT[jc] + emb[jc];
    if (rg < 4) *wptr[1] = __expf(score);            // step 1 reads buf 1
    if (u == 0) sig_sh[h][1] = score;                // shift for step 2
    float sigma = 0.f;

    // 4-deep emission/mask prefetch (this lane's score column only)
    float emv[4], emn[4];
    int   mkv[4], mkn[4];
#pragma unroll
    for (int k = 0; k < 4; ++k) { emv[k] = emb[(1 + k) * T + jc]; mkv[k] = mk[1 + k]; }
    __syncthreads();

    const bool lb0 = (rg & 1) != 0, lb1 = (rg & 2) != 0;

    for (int s0 = 1; s0 < SLEN; s0 += 4) {
#pragma unroll
        for (int k = 0; k < 4; ++k) {
            int ss = s0 + 4 + k; ss = (ss < SLEN) ? ss : (SLEN - 1);
            emn[k] = emb[ss * T + jc];
            mkn[k] = mk[ss];
        }
#pragma unroll
        for (int k = 0; k < 4; ++k) {
            const int s = s0 + k;
            if (s < SLEN) {                          // uniform guard (511 steps)
                const int cur = (1 + k) & 1;         // == s&1: compile-time
                float a0 = 0.f, a1 = 0.f, a2 = 0.f, a3 = 0.f;
#pragma unroll
                for (int i = 0; i < 4; ++i) {
                    const float4 pv = *paddr[cur][i];          // conflict-free
                    a0 = fmaf(pv.x, Ef[i][0].x, a0); a0 = fmaf(pv.y, Ef[i][0].y, a0);
                    a0 = fmaf(pv.z, Ef[i][0].z, a0); a0 = fmaf(pv.w, Ef[i][0].w, a0);
                    a1 = fmaf(pv.x, Ef[i][1].x, a1); a1 = fmaf(pv.y, Ef[i][1].y, a1);
                    a1 = fmaf(pv.z, Ef[i][1].z, a1); a1 = fmaf(pv.w, Ef[i][1].w, a1);
                    a2 = fmaf(pv.x, Ef[i][2].x, a2); a2 = fmaf(pv.y, Ef[i][2].y, a2);
                    a2 = fmaf(pv.z, Ef[i][2].z, a2); a2 = fmaf(pv.w, Ef[i][2].w, a2);
                    a3 = fmaf(pv.x, Ef[i][3].x, a3); a3 = fmaf(pv.y, Ef[i][3].y, a3);
                    a3 = fmaf(pv.z, Ef[i][3].z, a3); a3 = fmaf(pv.w, Ef[i][3].w, a3);
                }
                // Value-routing butterfly: lane rg ends with col q=rg&3 total.
                // Stage 1 (xor1): pair-sums of a0/a1 and a2/a3.
                float P  = (lb0 ? a1 : a0) + __shfl_xor(lb0 ? a0 : a1, 1);
                float P2 = (lb0 ? a3 : a2) + __shfl_xor(lb0 ? a2 : a3, 1);
                // Stage 2 (xor2): route P vs P2.
                float t  = (lb1 ? P2 : P) + __shfl_xor(lb1 ? P : P2, 2);
                // Stage 3 (xor4): rg and rg+4 hold same column.
                t += __shfl_xor(t, 4);
                const float sig_next = sig_sh[h][cur];
                const float n = sigma + __logf(t) + emv[k];
                score = (mkv[k] > 0) ? n : score;
                const float pp = __expf(score - sig_next);
                if (rg < 4) *wptr[cur ^ 1] = pp;
                if (u == 0) sig_sh[h][cur ^ 1] = score;
                sigma = sig_next;
                __syncthreads();
            }
        }
#pragma unroll
        for (int k = 0; k < 4; ++k) { emv[k] = emn[k]; mkv[k] = mkn[k]; }
    }

    // ---- denominator: logsumexp over cols; each col held by 2 lanes (x0.5) ----
    const int wid = tid >> 6;          // waves 0-3 = h0, 4-7 = h1
    float v = score + endT[jc];
    float m = v;
#pragma unroll
    for (int off = 32; off; off >>= 1) m = fmaxf(m, __shfl_xor(m, off));
    if ((tid & 63) == 0) redm[wid] = m;
    __syncthreads();
    float M = redm[4 * h];
#pragma unroll
    for (int i = 1; i < 4; ++i) M = fmaxf(M, redm[4 * h + i]);
    float sm = __expf(v - M) * 0.5f;   // duplicate factor
#pragma unroll
    for (int off = 32; off; off >>= 1) sm += __shfl_xor(sm, off);
    if ((tid & 63) == 0) reds[wid] = sm;

    // ---- numerator: 2 strided steps per thread ----
    const int* tg = tags + (size_t)b * SLEN;
    float nv = 0.f; int cnt = 0;
#pragma unroll
    for (int rep = 0; rep < 2; ++rep) {
        const int s = u + 256 * rep;
        const int mm = mk[s];
        cnt += (mm != 0);
        if (s >= 1 && mm > 0)
            nv += trans[tg[s - 1] * T + tg[s]] + emb[s * T + tg[s]];
    }
#pragma unroll
    for (int off = 32; off; off >>= 1) {
        nv  += __shfl_xor(nv, off);
        cnt += __shfl_xor(cnt, off);
    }
    if ((tid & 63) == 0) { redn[wid] = nv; redc[wid] = cnt; }
    __syncthreads();
    if (u == 0) {
        float ssum = 0.f, nsum = 0.f; int seqlen = 0;
#pragma unroll
        for (int i = 0; i < 4; ++i) {
            ssum += reds[4 * h + i]; nsum += redn[4 * h + i]; seqlen += redc[4 * h + i];
        }
        const float denom = M + __logf(ssum);
        const int t0 = tg[0], tl = tg[seqlen - 1];
        ws[b] = (startT[t0] + emb[t0] + endT[tl] + nsum) - denom;
    }
}

__global__ __launch_bounds__(256) void reduce_kernel(
    const float* __restrict__ ws, float* __restrict__ out)
{
    const int t = threadIdx.x;          // one block of 256
    float local = 0.f;
    for (int i = t; i < BATCH; i += 256) local += ws[i];
    __shared__ float rf[256];
    rf[t] = local;
    __syncthreads();
    for (int off = 128; off > 0; off >>= 1) {
        if (t < off) rf[t] += rf[t + off];
        __syncthreads();
    }
    if (t == 0) out[0] = rf[0];
}

extern "C" void kernel_launch(void* const* d_in, const int* in_sizes, int n_in,
                              void* d_out, int out_size, void* d_ws, size_t ws_size,
                              hipStream_t stream)
{
    const float* emissions = (const float*)d_in[0];
    const int*   tags      = (const int*)d_in[1];
    const int*   mask      = (const int*)d_in[2];
    const float* startT    = (const float*)d_in[3];
    const float* endT      = (const float*)d_in[4];
    const float* trans     = (const float*)d_in[5];
    float* out = (float*)d_out;
    float* ws  = (float*)d_ws;          // BATCH floats of per-batch partials

    fwd_kernel<<<BATCH / 2, 512, 0, stream>>>(emissions, tags, mask, startT, endT, trans, ws);
    reduce_kernel<<<1, 256, 0, stream>>>(ws, out);
}

// Round 7
// 399.152 us; speedup vs baseline: 1.0490x; 1.0259x over previous
//
#include <hip/hip_runtime.h>
#include <math.h>

// CRF log-likelihood, B=512, S=512, T=128.
// ROUND 7: register-residence fix. Six-round evidence: R4/R5 were bound by
// DS-instr throughput (16 waves x 8 ds_read_b128 x ~11cyc = 1408 cyc/step ==
// observed); R6 cut DS 4x and exposed a VALU wall: 800 VALU-cyc/SIMD-step =
// ~200 instr/lane-step vs ~104 static -- one extra op per fmac. VGPR_Count=60
// with a 64-float E fragment proves E sat in AGPRs (gfx950 AGPR-first spill),
// each fmac paying a copy. Fix: amdgpu_waves_per_eu(2,2) -- max=2 kills the
// occupancy incentive (we are grid-limited to 8 waves/CU anyway) so the RA
// keeps E in arch VGPRs. Plus instruction diet: LDS reads via precomputed
// 32-bit LDS pointers + compile-time buffer immediates; emission/mask
// addressing via uniform row pointers (SALU).
// Structure unchanged from R6 (verified absmax 0.0): block = 512 thr = TWO
// batches (h=tid>>8); per batch rg=u&7 (16-row groups), cg=u>>3 (4-col
// groups); rotated read order craw[i]=4rg+((i+rg)&3) + xor-4 storage swizzle
// -> SQ_LDS_BANK_CONFLICT == 0 (R6-verified). 3-shuffle value-routing
// butterfly; one barrier/step; sigma = col-0 score, 1-step delayed.

#define T 128
#define SLEN 512
#define BATCH 512

__global__ __launch_bounds__(512, 2)
__attribute__((amdgpu_waves_per_eu(2, 2)))
void fwd_kernel(
    const float* __restrict__ em, const int* __restrict__ tags,
    const int* __restrict__ mask, const float* __restrict__ startT,
    const float* __restrict__ endT, const float* __restrict__ trans,
    float* __restrict__ ws)
{
    const int tid = threadIdx.x;
    const int h   = tid >> 8;          // batch half
    const int u   = tid & 255;
    const int rg  = u & 7;             // row group: 16 rows
    const int cg  = u >> 3;            // col group: 4 cols (0..31)
    const int q   = rg & 3;            // this lane's score column within group
    const int b   = 2 * blockIdx.x + h;
    const int jc  = 4 * cg + q;        // score column
    const float* emb = em + (size_t)b * SLEN * T;
    const int*   mk  = mask + (size_t)b * SLEN;

    // Chunk schedule: rotated + storage-swizzled (R6: conflict-free).
    int craw[4], slot[4];
#pragma unroll
    for (int i = 0; i < 4; ++i) {
        craw[i] = 4 * rg + ((i + rg) & 3);
        slot[i] = craw[i] ^ ((craw[i] & 16) ? 4 : 0);
    }

    // E fragment: Ef[i][qq] = exp(trans[4*craw[i]+k][4cg+qq]), k=0..3 in xyzw.
    float4 Ef[4][4];
#pragma unroll
    for (int i = 0; i < 4; ++i) {
        const int r0 = 4 * craw[i];
#pragma unroll
        for (int qq = 0; qq < 4; ++qq) {
            const int col = 4 * cg + qq;
            Ef[i][qq].x = __expf(trans[(r0 + 0) * T + col]);
            Ef[i][qq].y = __expf(trans[(r0 + 1) * T + col]);
            Ef[i][qq].z = __expf(trans[(r0 + 2) * T + col]);
            Ef[i][qq].w = __expf(trans[(r0 + 3) * T + col]);
        }
    }

    __shared__ __align__(16) float4 psh[2][2][32];   // [h][buf][slot]
    __shared__ float sig_sh[2][2];                   // [h][buf]
    __shared__ float redm[8], reds[8], redn[8];
    __shared__ int   redc[8];

    // 32-bit LDS pointers, buffer selected by compile-time immediate (+512B).
    const char* rp[4];
#pragma unroll
    for (int i = 0; i < 4; ++i)
        rp[i] = (const char*)&psh[h][0][0] + slot[i] * 16;
    const int scg = cg ^ ((cg & 16) ? 4 : 0);        // write slot for col jc
    char* wp = (char*)&psh[h][0][0] + scg * 16 + q * 4;

    // alpha_0
    float score = startT[jc] + emb[jc];
    if (rg < 4) *(float*)(wp + 512) = __expf(score); // step 1 reads buf 1
    if (u == 0) sig_sh[h][1] = score;                // shift for step 2
    float sigma = 0.f;

    // 4-deep emission/mask prefetch (uniform row pointers -> SALU addressing)
    float emv[4], emn[4];
    int   mkv[4], mkn[4];
#pragma unroll
    for (int k = 0; k < 4; ++k) { emv[k] = (emb + (1 + k) * T)[jc]; mkv[k] = mk[1 + k]; }
    __syncthreads();

    const bool lb0 = (rg & 1) != 0, lb1 = (rg & 2) != 0;

    for (int s0 = 1; s0 < SLEN; s0 += 4) {
#pragma unroll
        for (int k = 0; k < 4; ++k) {
            int ss = s0 + 4 + k; ss = (ss < SLEN) ? ss : (SLEN - 1);  // uniform
            emn[k] = (emb + ss * T)[jc];
            mkn[k] = mk[ss];
        }
#pragma unroll
        for (int k = 0; k < 4; ++k) {
            const int s = s0 + k;
            if (s < SLEN) {                          // uniform guard (511 steps)
                const int cur = (1 + k) & 1;         // == s&1: compile-time
                float a0 = 0.f, a1 = 0.f, a2 = 0.f, a3 = 0.f;
#pragma unroll
                for (int i = 0; i < 4; ++i) {
                    const float4 pv = *(const float4*)(rp[i] + cur * 512);
                    a0 = fmaf(pv.x, Ef[i][0].x, a0); a0 = fmaf(pv.y, Ef[i][0].y, a0);
                    a0 = fmaf(pv.z, Ef[i][0].z, a0); a0 = fmaf(pv.w, Ef[i][0].w, a0);
                    a1 = fmaf(pv.x, Ef[i][1].x, a1); a1 = fmaf(pv.y, Ef[i][1].y, a1);
                    a1 = fmaf(pv.z, Ef[i][1].z, a1); a1 = fmaf(pv.w, Ef[i][1].w, a1);
                    a2 = fmaf(pv.x, Ef[i][2].x, a2); a2 = fmaf(pv.y, Ef[i][2].y, a2);
                    a2 = fmaf(pv.z, Ef[i][2].z, a2); a2 = fmaf(pv.w, Ef[i][2].w, a2);
                    a3 = fmaf(pv.x, Ef[i][3].x, a3); a3 = fmaf(pv.y, Ef[i][3].y, a3);
                    a3 = fmaf(pv.z, Ef[i][3].z, a3); a3 = fmaf(pv.w, Ef[i][3].w, a3);
                }
                // Value-routing butterfly: lane rg ends with col q=rg&3 total.
                float P  = (lb0 ? a1 : a0) + __shfl_xor(lb0 ? a0 : a1, 1);
                float P2 = (lb0 ? a3 : a2) + __shfl_xor(lb0 ? a2 : a3, 1);
                float t  = (lb1 ? P2 : P) + __shfl_xor(lb1 ? P : P2, 2);
                t += __shfl_xor(t, 4);
                const float sig_next = sig_sh[h][cur];
                const float n = sigma + __logf(t) + emv[k];
                score = (mkv[k] > 0) ? n : score;
                const float pp = __expf(score - sig_next);
                if (rg < 4) *(float*)(wp + (cur ^ 1) * 512) = pp;
                if (u == 0) sig_sh[h][cur ^ 1] = score;
                sigma = sig_next;
                __syncthreads();
            }
        }
#pragma unroll
        for (int k = 0; k < 4; ++k) { emv[k] = emn[k]; mkv[k] = mkn[k]; }
    }

    // ---- denominator: logsumexp over cols; each col held by 2 lanes (x0.5) ----
    const int wid = tid >> 6;          // waves 0-3 = h0, 4-7 = h1
    float v = score + endT[jc];
    float m = v;
#pragma unroll
    for (int off = 32; off; off >>= 1) m = fmaxf(m, __shfl_xor(m, off));
    if ((tid & 63) == 0) redm[wid] = m;
    __syncthreads();
    float M = redm[4 * h];
#pragma unroll
    for (int i = 1; i < 4; ++i) M = fmaxf(M, redm[4 * h + i]);
    float sm = __expf(v - M) * 0.5f;   // duplicate factor
#pragma unroll
    for (int off = 32; off; off >>= 1) sm += __shfl_xor(sm, off);
    if ((tid & 63) == 0) reds[wid] = sm;

    // ---- numerator: 2 strided steps per thread ----
    const int* tg = tags + (size_t)b * SLEN;
    float nv = 0.f; int cnt = 0;
#pragma unroll
    for (int rep = 0; rep < 2; ++rep) {
        const int s = u + 256 * rep;
        const int mm = mk[s];
        cnt += (mm != 0);
        if (s >= 1 && mm > 0)
            nv += trans[tg[s - 1] * T + tg[s]] + emb[s * T + tg[s]];
    }
#pragma unroll
    for (int off = 32; off; off >>= 1) {
        nv  += __shfl_xor(nv, off);
        cnt += __shfl_xor(cnt, off);
    }
    if ((tid & 63) == 0) { redn[wid] = nv; redc[wid] = cnt; }
    __syncthreads();
    if (u == 0) {
        float ssum = 0.f, nsum = 0.f; int seqlen = 0;
#pragma unroll
        for (int i = 0; i < 4; ++i) {
            ssum += reds[4 * h + i]; nsum += redn[4 * h + i]; seqlen += redc[4 * h + i];
        }
        const float denom = M + __logf(ssum);
        const int t0 = tg[0], tl = tg[seqlen - 1];
        ws[b] = (startT[t0] + emb[t0] + endT[tl] + nsum) - denom;
    }
}

__global__ __launch_bounds__(256) void reduce_kernel(
    const float* __restrict__ ws, float* __restrict__ out)
{
    const int t = threadIdx.x;          // one block of 256
    float local = 0.f;
    for (int i = t; i < BATCH; i += 256) local += ws[i];
    __shared__ float rf[256];
    rf[t] = local;
    __syncthreads();
    for (int off = 128; off > 0; off >>= 1) {
        if (t < off) rf[t] += rf[t + off];
        __syncthreads();
    }
    if (t == 0) out[0] = rf[0];
}

extern "C" void kernel_launch(void* const* d_in, const int* in_sizes, int n_in,
                              void* d_out, int out_size, void* d_ws, size_t ws_size,
                              hipStream_t stream)
{
    const float* emissions = (const float*)d_in[0];
    const int*   tags      = (const int*)d_in[1];
    const int*   mask      = (const int*)d_in[2];
    const float* startT    = (const float*)d_in[3];
    const float* endT      = (const float*)d_in[4];
    const float* trans     = (const float*)d_in[5];
    float* out = (float*)d_out;
    float* ws  = (float*)d_ws;          // BATCH floats of per-batch partials

    fwd_kernel<<<BATCH / 2, 512, 0, stream>>>(emissions, tags, mask, startT, endT, trans, ws);
    reduce_kernel<<<1, 256, 0, stream>>>(ws, out);
}

// Round 8
// 398.026 us; speedup vs baseline: 1.0520x; 1.0028x over previous
//
#include <hip/hip_runtime.h>
#include <math.h>

// CRF log-likelihood, B=512, S=512, T=128.
// ROUND 8: concurrency fix. R7 evidence: grid was 256 blocks = 1 block/CU;
// all 8 waves lockstepped on one barrier -> the per-step dependent chain
// (barrier, ds_read ~120cyc, 64 fmac, 3 shuffle stages, log, exp, ds_write,
// barrier) = ~1277 cyc was fully exposed, with nothing on the CU to overlap.
// That's why the R6 4x LDS cut and R7 diets each bought only ~3%.
// Fix: ONE BATCH PER BLOCK (256 thr, 4 waves), grid 512 = 2 independent
// blocks/CU with separate barriers -> two chains interleave (sleep of one
// fills issue of the other). Per-CU step-pair resources are small (DS ~352,
// VALU ~360 cyc) so step time -> ~L/2.  Chain diet: 64 fmac -> 32
// v_pk_fma_f32 via float2 elementwise fma.
// Intra-batch structure = R6/R7 proven (absmax 0.0, conflicts 0):
//   rg=tid&7 (16-row groups), cg=tid>>3 (4-col groups), q=rg&3;
//   rotated read order craw[i]=4rg+((i+rg)&3), xor-4 storage swizzle;
//   3-shuffle value-routing butterfly; one barrier/step;
//   sigma = col-0 score, 1-step delayed via sig_sh.

#define T 128
#define SLEN 512
#define BATCH 512

typedef float v2f __attribute__((ext_vector_type(2)));

__global__ __launch_bounds__(256, 2) void fwd_kernel(
    const float* __restrict__ em, const int* __restrict__ tags,
    const int* __restrict__ mask, const float* __restrict__ startT,
    const float* __restrict__ endT, const float* __restrict__ trans,
    float* __restrict__ ws)
{
    const int tid = threadIdx.x;       // 0..255
    const int rg  = tid & 7;           // row group: 16 rows
    const int cg  = tid >> 3;          // col group: 4 cols (0..31)
    const int q   = rg & 3;            // this lane's score column within group
    const int b   = blockIdx.x;
    const int jc  = 4 * cg + q;        // score column
    const float* emb = em + (size_t)b * SLEN * T;
    const int*   mk  = mask + (size_t)b * SLEN;

    // Chunk schedule: rotated + storage-swizzled (R6-verified conflict-free).
    int craw[4], slot[4];
#pragma unroll
    for (int i = 0; i < 4; ++i) {
        craw[i] = 4 * rg + ((i + rg) & 3);
        slot[i] = craw[i] ^ ((craw[i] & 16) ? 4 : 0);
    }

    // E fragment as packed pairs: Elo[i][qq] = rows (r0,r0+1), Ehi = (r0+2,r0+3).
    v2f Elo[4][4], Ehi[4][4];
#pragma unroll
    for (int i = 0; i < 4; ++i) {
        const int r0 = 4 * craw[i];
#pragma unroll
        for (int qq = 0; qq < 4; ++qq) {
            const int col = 4 * cg + qq;
            Elo[i][qq] = (v2f){ __expf(trans[(r0 + 0) * T + col]),
                                __expf(trans[(r0 + 1) * T + col]) };
            Ehi[i][qq] = (v2f){ __expf(trans[(r0 + 2) * T + col]),
                                __expf(trans[(r0 + 3) * T + col]) };
        }
    }

    __shared__ __align__(16) float4 psh[2][32];      // [buf][slot]
    __shared__ float sig_sh[2];
    __shared__ float redm[4], reds[4], redn[4];
    __shared__ int   redc[4];

    // 32-bit LDS pointers; buffer = compile-time +512B immediate.
    const char* rp[4];
#pragma unroll
    for (int i = 0; i < 4; ++i)
        rp[i] = (const char*)&psh[0][0] + slot[i] * 16;
    const int scg = cg ^ ((cg & 16) ? 4 : 0);        // write slot for col jc
    char* wp = (char*)&psh[0][0] + scg * 16 + q * 4;

    // alpha_0
    float score = startT[jc] + emb[jc];
    if (rg < 4) *(float*)(wp + 512) = __expf(score); // step 1 reads buf 1
    if (tid == 0) sig_sh[1] = score;                 // shift for step 2
    float sigma = 0.f;

    // 4-deep emission/mask prefetch
    float emv[4], emn[4];
    int   mkv[4], mkn[4];
#pragma unroll
    for (int k = 0; k < 4; ++k) { emv[k] = (emb + (1 + k) * T)[jc]; mkv[k] = mk[1 + k]; }
    __syncthreads();

    const bool lb0 = (rg & 1) != 0, lb1 = (rg & 2) != 0;

    for (int s0 = 1; s0 < SLEN; s0 += 4) {
#pragma unroll
        for (int k = 0; k < 4; ++k) {
            int ss = s0 + 4 + k; ss = (ss < SLEN) ? ss : (SLEN - 1);  // uniform
            emn[k] = (emb + ss * T)[jc];
            mkn[k] = mk[ss];
        }
#pragma unroll
        for (int k = 0; k < 4; ++k) {
            const int s = s0 + k;
            if (s < SLEN) {                          // uniform guard (511 steps)
                const int cur = (1 + k) & 1;         // == s&1: compile-time
                v2f a0 = {0.f, 0.f}, a1 = a0, a2 = a0, a3 = a0;
#pragma unroll
                for (int i = 0; i < 4; ++i) {
                    const float4 pv = *(const float4*)(rp[i] + cur * 512);
                    const v2f plo = {pv.x, pv.y}, phi = {pv.z, pv.w};
                    a0 = __builtin_elementwise_fma(plo, Elo[i][0], a0);
                    a0 = __builtin_elementwise_fma(phi, Ehi[i][0], a0);
                    a1 = __builtin_elementwise_fma(plo, Elo[i][1], a1);
                    a1 = __builtin_elementwise_fma(phi, Ehi[i][1], a1);
                    a2 = __builtin_elementwise_fma(plo, Elo[i][2], a2);
                    a2 = __builtin_elementwise_fma(phi, Ehi[i][2], a2);
                    a3 = __builtin_elementwise_fma(plo, Elo[i][3], a3);
                    a3 = __builtin_elementwise_fma(phi, Ehi[i][3], a3);
                }
                const float c0 = a0.x + a0.y, c1 = a1.x + a1.y;
                const float c2 = a2.x + a2.y, c3 = a3.x + a3.y;
                // Value-routing butterfly: lane rg ends with col q=rg&3 total.
                float P  = (lb0 ? c1 : c0) + __shfl_xor(lb0 ? c0 : c1, 1);
                float P2 = (lb0 ? c3 : c2) + __shfl_xor(lb0 ? c2 : c3, 1);
                float t  = (lb1 ? P2 : P) + __shfl_xor(lb1 ? P : P2, 2);
                t += __shfl_xor(t, 4);
                const float sig_next = sig_sh[cur];
                const float n = sigma + __logf(t) + emv[k];
                score = (mkv[k] > 0) ? n : score;
                const float pp = __expf(score - sig_next);
                if (rg < 4) *(float*)(wp + (cur ^ 1) * 512) = pp;
                if (tid == 0) sig_sh[cur ^ 1] = score;
                sigma = sig_next;
                __syncthreads();
            }
        }
#pragma unroll
        for (int k = 0; k < 4; ++k) { emv[k] = emn[k]; mkv[k] = mkn[k]; }
    }

    // ---- denominator: logsumexp over cols; each col held by 2 lanes (x0.5) ----
    const int wid = tid >> 6;          // wave 0..3
    float v = score + endT[jc];
    float m = v;
#pragma unroll
    for (int off = 32; off; off >>= 1) m = fmaxf(m, __shfl_xor(m, off));
    if ((tid & 63) == 0) redm[wid] = m;
    __syncthreads();
    float M = redm[0];
#pragma unroll
    for (int i = 1; i < 4; ++i) M = fmaxf(M, redm[i]);
    float sm = __expf(v - M) * 0.5f;   // duplicate factor
#pragma unroll
    for (int off = 32; off; off >>= 1) sm += __shfl_xor(sm, off);
    if ((tid & 63) == 0) reds[wid] = sm;

    // ---- numerator: 2 strided steps per thread ----
    const int* tg = tags + (size_t)b * SLEN;
    float nv = 0.f; int cnt = 0;
#pragma unroll
    for (int rep = 0; rep < 2; ++rep) {
        const int s = tid + 256 * rep;
        const int mm = mk[s];
        cnt += (mm != 0);
        if (s >= 1 && mm > 0)
            nv += trans[tg[s - 1] * T + tg[s]] + emb[s * T + tg[s]];
    }
#pragma unroll
    for (int off = 32; off; off >>= 1) {
        nv  += __shfl_xor(nv, off);
        cnt += __shfl_xor(cnt, off);
    }
    if ((tid & 63) == 0) { redn[wid] = nv; redc[wid] = cnt; }
    __syncthreads();
    if (tid == 0) {
        float ssum = 0.f, nsum = 0.f; int seqlen = 0;
#pragma unroll
        for (int i = 0; i < 4; ++i) {
            ssum += reds[i]; nsum += redn[i]; seqlen += redc[i];
        }
        const float denom = M + __logf(ssum);
        const int t0 = tg[0], tl = tg[seqlen - 1];
        ws[b] = (startT[t0] + emb[t0] + endT[tl] + nsum) - denom;
    }
}

__global__ __launch_bounds__(256) void reduce_kernel(
    const float* __restrict__ ws, float* __restrict__ out)
{
    const int t = threadIdx.x;          // one block of 256
    float local = 0.f;
    for (int i = t; i < BATCH; i += 256) local += ws[i];
    __shared__ float rf[256];
    rf[t] = local;
    __syncthreads();
    for (int off = 128; off > 0; off >>= 1) {
        if (t < off) rf[t] += rf[t + off];
        __syncthreads();
    }
    if (t == 0) out[0] = rf[0];
}

extern "C" void kernel_launch(void* const* d_in, const int* in_sizes, int n_in,
                              void* d_out, int out_size, void* d_ws, size_t ws_size,
                              hipStream_t stream)
{
    const float* emissions = (const float*)d_in[0];
    const int*   tags      = (const int*)d_in[1];
    const int*   mask      = (const int*)d_in[2];
    const float* startT    = (const float*)d_in[3];
    const float* endT      = (const float*)d_in[4];
    const float* trans     = (const float*)d_in[5];
    float* out = (float*)d_out;
    float* ws  = (float*)d_ws;          // BATCH floats of per-batch partials

    fwd_kernel<<<BATCH, 256, 0, stream>>>(emissions, tags, mask, startT, endT, trans, ws);
    reduce_kernel<<<1, 256, 0, stream>>>(ws, out);
}

// Round 9
// 383.493 us; speedup vs baseline: 1.0918x; 1.0379x over previous
//
#include <hip/hip_runtime.h>
#include <math.h>

// CRF log-likelihood, B=512, S=512, T=128.
// ROUND 9: chain-shortening via SCALED-LINEAR domain. R8 proved duration =
// 511 x per-step dependent-chain latency (~1277 cyc); concurrency can't help
// (all batches already parallel). Old chain contained sig-read -> logf ->
// select -> expf (~200+ cyc serial). New recursion (linear domain):
//   p_next_j = (sum_i p_i E_ij) * eem_j * c,  eem = exp(em) (applied at
//   PREFETCH, off-chain), c = 1/p_0(cur buffer) (broadcast ds_read_b32 at
//   step start + v_rcp, off-chain). Self-normalizing: p ~ 128*e^em.
//   Exact accounting: Ld += log(sref) per step (off-chain, double acc);
//   denom = log(sum_j p_j e^endT_j) + Ld.  mask=0 step: p_next = p_prev * c.
// Chain now: barrier -> ds_read(120) -> fma(~40) -> 3 shfl -> mul -> ds_write
// -> barrier  ~= 550-650 cyc (was 1277).
// Structure from R6-R8 (verified: absmax 0.0, SQ_LDS_BANK_CONFLICT 0):
// 256 thr/batch, rg=tid&7 (16-row groups), cg=tid>>3 (4-col groups), q=rg&3;
// rotated read order craw[i]=4rg+((i+rg)&3) + xor-4 storage swizzle;
// 3-shuffle value-routing butterfly; one barrier/step.

#define T 128
#define SLEN 512
#define BATCH 512

typedef float v2f __attribute__((ext_vector_type(2)));

__global__ __launch_bounds__(256, 2) void fwd_kernel(
    const float* __restrict__ em, const int* __restrict__ tags,
    const int* __restrict__ mask, const float* __restrict__ startT,
    const float* __restrict__ endT, const float* __restrict__ trans,
    float* __restrict__ ws)
{
    const int tid = threadIdx.x;       // 0..255
    const int rg  = tid & 7;           // row group: 16 rows
    const int cg  = tid >> 3;          // col group: 4 cols (0..31)
    const int q   = rg & 3;            // this lane's score column within group
    const int b   = blockIdx.x;
    const int jc  = 4 * cg + q;        // score column
    const float* emb = em + (size_t)b * SLEN * T;
    const int*   mk  = mask + (size_t)b * SLEN;

    // Chunk schedule: rotated + storage-swizzled (R6-verified conflict-free).
    int craw[4], slot[4];
#pragma unroll
    for (int i = 0; i < 4; ++i) {
        craw[i] = 4 * rg + ((i + rg) & 3);
        slot[i] = craw[i] ^ ((craw[i] & 16) ? 4 : 0);
    }

    // E fragment as packed pairs: Elo[i][qq] = rows (r0,r0+1), Ehi = (r0+2,r0+3).
    v2f Elo[4][4], Ehi[4][4];
#pragma unroll
    for (int i = 0; i < 4; ++i) {
        const int r0 = 4 * craw[i];
#pragma unroll
        for (int qq = 0; qq < 4; ++qq) {
            const int col = 4 * cg + qq;
            Elo[i][qq] = (v2f){ __expf(trans[(r0 + 0) * T + col]),
                                __expf(trans[(r0 + 1) * T + col]) };
            Ehi[i][qq] = (v2f){ __expf(trans[(r0 + 2) * T + col]),
                                __expf(trans[(r0 + 3) * T + col]) };
        }
    }

    __shared__ __align__(16) float4 psh[2][32];      // [buf][slot]; 512B apart
    __shared__ float reds[4], redn[4];
    __shared__ int   redc[4];

    // 32-bit LDS pointers; buffer = compile-time +512B immediate.
    const char* rp[4];
#pragma unroll
    for (int i = 0; i < 4; ++i)
        rp[i] = (const char*)&psh[0][0] + slot[i] * 16;
    const int scg = cg ^ ((cg & 16) ? 4 : 0);        // write slot for col jc
    char* wp = (char*)&psh[0][0] + scg * 16 + q * 4;
    const char* srefp = (const char*)&psh[0][0];     // col 0 = slot 0, word 0

    // alpha_0 in linear domain: p0 = exp(start + em0)
    float pprev = __expf(startT[jc] + emb[jc]);
    if (rg < 4) *(float*)(wp + 512) = pprev;         // step 1 reads buf 1
    double Ld = 0.0;                                  // sum of log(sref)

    // 4-deep emission/mask prefetch; eem = exp(em) applied off-chain here.
    float emv[4], emn[4];
    int   mkv[4], mkn[4];
#pragma unroll
    for (int k = 0; k < 4; ++k) {
        emv[k] = __expf((emb + (1 + k) * T)[jc]);
        mkv[k] = mk[1 + k];
    }
    __syncthreads();

    const bool lb0 = (rg & 1) != 0, lb1 = (rg & 2) != 0;

    for (int s0 = 1; s0 < SLEN; s0 += 4) {
#pragma unroll
        for (int k = 0; k < 4; ++k) {
            int ss = s0 + 4 + k; ss = (ss < SLEN) ? ss : (SLEN - 1);  // uniform
            emn[k] = (emb + ss * T)[jc];
            mkn[k] = mk[ss];
        }
#pragma unroll
        for (int k = 0; k < 4; ++k) {
            const int s = s0 + k;
            if (s < SLEN) {                          // uniform guard (511 steps)
                const int cur = (1 + k) & 1;         // == s&1: compile-time
                // Off-chain: normalizer from col-0 of current buffer.
                const float sref0 = *(const float*)(srefp + cur * 512);
                const float srefc = fmaxf(sref0, 1e-30f);
                const float cc = __builtin_amdgcn_rcpf(srefc);
                const float f  = emv[k] * cc;        // eem * c
                Ld += (double)__logf(srefc);         // exact accounting

                v2f a0 = {0.f, 0.f}, a1 = a0, a2 = a0, a3 = a0;
#pragma unroll
                for (int i = 0; i < 4; ++i) {
                    const float4 pv = *(const float4*)(rp[i] + cur * 512);
                    const v2f plo = {pv.x, pv.y}, phi = {pv.z, pv.w};
                    a0 = __builtin_elementwise_fma(plo, Elo[i][0], a0);
                    a0 = __builtin_elementwise_fma(phi, Ehi[i][0], a0);
                    a1 = __builtin_elementwise_fma(plo, Elo[i][1], a1);
                    a1 = __builtin_elementwise_fma(phi, Ehi[i][1], a1);
                    a2 = __builtin_elementwise_fma(plo, Elo[i][2], a2);
                    a2 = __builtin_elementwise_fma(phi, Ehi[i][2], a2);
                    a3 = __builtin_elementwise_fma(plo, Elo[i][3], a3);
                    a3 = __builtin_elementwise_fma(phi, Ehi[i][3], a3);
                }
                const float c0 = a0.x + a0.y, c1 = a1.x + a1.y;
                const float c2 = a2.x + a2.y, c3 = a3.x + a3.y;
                // Value-routing butterfly: lane ends with col q=rg&3 total.
                float P  = (lb0 ? c1 : c0) + __shfl_xor(lb0 ? c0 : c1, 1);
                float P2 = (lb0 ? c3 : c2) + __shfl_xor(lb0 ? c2 : c3, 1);
                float t  = (lb1 ? P2 : P) + __shfl_xor(lb1 ? P : P2, 2);
                t += __shfl_xor(t, 4);
                // Linear-domain update; mask=0 keeps alpha (p scales by c only).
                const float pn = t * f;
                const float pm = pprev * cc;
                pprev = (mkv[k] > 0) ? pn : pm;      // all lanes track
                if (rg < 4) *(float*)(wp + (cur ^ 1) * 512) = pprev;
                __syncthreads();
            }
        }
#pragma unroll
        for (int k = 0; k < 4; ++k) { emv[k] = __expf(emn[k]); mkv[k] = mkn[k]; }
    }

    // ---- denominator: denom = log(sum_j p_j * exp(endT_j)) + Ld ----
    const int wid = tid >> 6;          // wave 0..3
    float sm = (rg < 4) ? pprev * __expf(endT[jc]) : 0.f;  // each col once
#pragma unroll
    for (int off = 32; off; off >>= 1) sm += __shfl_xor(sm, off);
    if ((tid & 63) == 0) reds[wid] = sm;

    // ---- numerator: 2 strided steps per thread ----
    const int* tg = tags + (size_t)b * SLEN;
    float nv = 0.f; int cnt = 0;
#pragma unroll
    for (int rep = 0; rep < 2; ++rep) {
        const int s = tid + 256 * rep;
        const int mm = mk[s];
        cnt += (mm != 0);
        if (s >= 1 && mm > 0)
            nv += trans[tg[s - 1] * T + tg[s]] + emb[s * T + tg[s]];
    }
#pragma unroll
    for (int off = 32; off; off >>= 1) {
        nv  += __shfl_xor(nv, off);
        cnt += __shfl_xor(cnt, off);
    }
    if ((tid & 63) == 0) { redn[wid] = nv; redc[wid] = cnt; }
    __syncthreads();
    if (tid == 0) {
        float ssum = 0.f, nsum = 0.f; int seqlen = 0;
#pragma unroll
        for (int i = 0; i < 4; ++i) {
            ssum += reds[i]; nsum += redn[i]; seqlen += redc[i];
        }
        const float denom = __logf(ssum) + (float)Ld;
        const int t0 = tg[0], tl = tg[seqlen - 1];
        ws[b] = (startT[t0] + emb[t0] + endT[tl] + nsum) - denom;
    }
}

__global__ __launch_bounds__(256) void reduce_kernel(
    const float* __restrict__ ws, float* __restrict__ out)
{
    const int t = threadIdx.x;          // one block of 256
    float local = 0.f;
    for (int i = t; i < BATCH; i += 256) local += ws[i];
    __shared__ float rf[256];
    rf[t] = local;
    __syncthreads();
    for (int off = 128; off > 0; off >>= 1) {
        if (t < off) rf[t] += rf[t + off];
        __syncthreads();
    }
    if (t == 0) out[0] = rf[0];
}

extern "C" void kernel_launch(void* const* d_in, const int* in_sizes, int n_in,
                              void* d_out, int out_size, void* d_ws, size_t ws_size,
                              hipStream_t stream)
{
    const float* emissions = (const float*)d_in[0];
    const int*   tags      = (const int*)d_in[1];
    const int*   mask      = (const int*)d_in[2];
    const float* startT    = (const float*)d_in[3];
    const float* endT      = (const float*)d_in[4];
    const float* trans     = (const float*)d_in[5];
    float* out = (float*)d_out;
    float* ws  = (float*)d_ws;          // BATCH floats of per-batch partials

    fwd_kernel<<<BATCH, 256, 0, stream>>>(emissions, tags, mask, startT, endT, trans, ws);
    reduce_kernel<<<1, 256, 0, stream>>>(ws, out);
}